// Round 6
// baseline (368.154 us; speedup 1.0000x reference)
//
#include <hip/hip_runtime.h>

#define BATCH   262144
#define NCODE   1024
#define DIM     64
#define BLOCK   256
#define NBLK    (BATCH / BLOCK)   // 1024 blocks for emit
#define MARGIN2 2e-5f             // s''-units (= 4e-5 in dist units, validated r2-r5)
#define QCAP    65536

// ws layout (bytes):
// [0, 8)               double dsum            -- fused loss accumulator
// [8, 12)              uint   dcount          -- emit completion counter
// [12, 16)             uint   qcount
// [1024, 5120)         float  c2[1024]
// [5120, 9216)         float  c2n[1024]       -- c2n[k] = -0.5f*c2[k]
// [16384, 278528)      ushort pack[131072]    -- codebook bf16 hi/lo, fragment-major
// [278528, 540672)     int    queue[65536]
// [540672, 802816)     float  cbT[65536]      -- codebook transposed [d][k]

typedef __attribute__((ext_vector_type(8))) short bf16x8;
typedef __attribute__((ext_vector_type(4))) float f32x4;

#define MFMA(a, b, c) __builtin_amdgcn_mfma_f32_16x16x32_bf16(a, b, c, 0, 0, 0)

// fp32 -> bf16 hi (RNE) + bf16 lo (RNE of exact residual)
__device__ __forceinline__ void split1(float f, unsigned short& h, unsigned short& l) {
    unsigned u = __float_as_uint(f);
    unsigned r = (u + 0x7fffu + ((u >> 16) & 1u)) >> 16;
    h = (unsigned short)r;
    float hf = __uint_as_float(r << 16);
    float lo = f - hf;                      // exact (Sterbenz)
    unsigned u2 = __float_as_uint(lo);
    l = (unsigned short)((u2 + 0x7fffu + ((u2 >> 16) & 1u)) >> 16);
}

// ---- fused prep: counters zero, cbT transpose, exact c2 (+ -c2/2), pack ----
__global__ __launch_bounds__(256) void prep_kernel(
        const float* __restrict__ cb, float* __restrict__ c2, float* __restrict__ c2n,
        float* __restrict__ cbT, unsigned short* __restrict__ pack,
        unsigned int* __restrict__ qcount, double* __restrict__ dsum,
        unsigned int* __restrict__ dcount)
{
    const int gid = blockIdx.x * 256 + threadIdx.x;           // 0..65535
    if (gid == 0) { *qcount = 0u; *dsum = 0.0; *dcount = 0u; } // re-zero each replay
    // transpose: cbT[d][k] = cb[k][d]
    cbT[(size_t)(gid & 63) * NCODE + (gid >> 6)] = cb[gid];
    // exact c2 (numpy pairwise order, 8 accumulators) — verified
    if (gid < NCODE) {
        const float* row = cb + (size_t)gid * DIM;
        float r[8];
#pragma unroll
        for (int j = 0; j < 8; ++j) r[j] = __fmul_rn(row[j], row[j]);
#pragma unroll
        for (int i = 8; i < DIM; i += 8) {
#pragma unroll
            for (int j = 0; j < 8; ++j) r[j] = __fadd_rn(r[j], __fmul_rn(row[i + j], row[i + j]));
        }
        const float v = __fadd_rn(__fadd_rn(__fadd_rn(r[0], r[1]), __fadd_rn(r[2], r[3])),
                                  __fadd_rn(__fadd_rn(r[4], r[5]), __fadd_rn(r[6], r[7])));
        c2[gid] = v;
        c2n[gid] = -0.5f * v;                 // exact scaling, screen-side only
    }
    // pack: fragment-major bf16 hi/lo
    if (gid < 4096) {
        const int t = gid >> 6, lane = gid & 63;
        const int c = t * 16 + (lane & 15);
        const int g = lane >> 4;
#pragma unroll
        for (int s = 0; s < 2; ++s) {
            const float* src = cb + (size_t)c * DIM + s * 32 + g * 8;
            bf16x8 hv, lv;
#pragma unroll
            for (int j = 0; j < 8; ++j) {
                unsigned short hh, ll; split1(src[j], hh, ll);
                hv[j] = (short)hh; lv[j] = (short)ll;
            }
            *(bf16x8*)(pack + ((size_t)(t * 4 + 2 * s + 0) * 64 + lane) * 8) = hv;
            *(bf16x8*)(pack + ((size_t)(t * 4 + 2 * s + 1) * 64 + lane) * 8) = lv;
        }
    }
}

// ---- MFMA screening: per-row best/second-best of s''(k) = cross(k) - c2[k]/2 ----
// argmax(s'') == argmin(dist). wave = 32 rows; block = 4 waves; grid = 2048.
// B is 256 KB, L1/L2-resident: load fragments DIRECTLY to VGPRs, double-buffered.
// No LDS, no barriers. __launch_bounds__(256,4) pins <=128 VGPR (4 waves/SIMD).
__global__ __launch_bounds__(256, 4) void screen_kernel(
        const float* __restrict__ z, const unsigned short* __restrict__ pack,
        const float* __restrict__ c2n, float* __restrict__ out_idx,
        int* __restrict__ queue, unsigned int* __restrict__ qcount)
{
    const int tid  = threadIdx.x;
    const int lane = tid & 63, wid = tid >> 6;
    const int col  = lane & 15, g = lane >> 4;
    const int rowbase = blockIdx.x * 128 + wid * 32;

    // A-frags: A[row = lane&15][k = 32*s + 8*g + j], in VGPRs for whole kernel
    bf16x8 Ah[2][2], Al[2][2];
#pragma unroll
    for (int rt = 0; rt < 2; ++rt)
#pragma unroll
        for (int s = 0; s < 2; ++s) {
            const float* zp = z + (size_t)(rowbase + rt * 16 + col) * DIM + s * 32 + g * 8;
            float tmp[8];
            *(float4*)(tmp)     = ((const float4*)zp)[0];
            *(float4*)(tmp + 4) = ((const float4*)zp)[1];
            bf16x8 hv, lv;
#pragma unroll
            for (int j = 0; j < 8; ++j) {
                unsigned short hh, ll; split1(tmp[j], hh, ll);
                hv[j] = (short)hh; lv[j] = (short)ll;
            }
            Ah[rt][s] = hv; Al[rt][s] = lv;
        }

    float b1[8], b2[8], bk[8];
#pragma unroll
    for (int i = 0; i < 8; ++i) {
        b1[i] = -__builtin_inff(); b2[i] = -__builtin_inff(); bk[i] = 0.f;
    }
    float codef = (float)col;

    // max-tracking; b2 = med3(s, b1_old, b2) is exact 2nd-max update given b2 <= b1
#define UPD(i, sv) { const float s_ = (sv); \
                     bk[i] = (s_ > b1[i]) ? codef : bk[i]; \
                     b2[i] = __builtin_amdgcn_fmed3f(s_, b1[i], b2[i]); \
                     b1[i] = fmaxf(b1[i], s_); }

    // one 16-code tile = 4 x bf16x8 fragments, loaded straight from pack (L1/L2 hit)
#define LOADB(BUF, t) { const unsigned short* p_ = pack + (size_t)(t) * 2048 + lane * 8; \
        BUF[0] = *(const bf16x8*)(p_);        BUF[1] = *(const bf16x8*)(p_ +  512); \
        BUF[2] = *(const bf16x8*)(p_ + 1024); BUF[3] = *(const bf16x8*)(p_ + 1536); }

    // cross = zhi*chi + zhi*clo + zlo*chi (lo*lo dropped, ~2^-18 rel);
    // acc C-in = -c2/2 folds the distance fma away. BUF: [0]=Bh0 [1]=Bl0 [2]=Bh1 [3]=Bl1
#define COMPUTE(BUF, cv) { \
_Pragma("unroll") \
    for (int rt = 0; rt < 2; ++rt) { \
        f32x4 acc = {cv, cv, cv, cv}; \
        acc = MFMA(Ah[rt][0], BUF[0], acc); acc = MFMA(Ah[rt][1], BUF[2], acc); \
        acc = MFMA(Ah[rt][0], BUF[1], acc); acc = MFMA(Al[rt][0], BUF[0], acc); \
        acc = MFMA(Ah[rt][1], BUF[3], acc); acc = MFMA(Al[rt][1], BUF[2], acc); \
_Pragma("unroll") \
        for (int reg = 0; reg < 4; ++reg) UPD(rt * 4 + reg, acc[reg]); \
    } \
    codef += 16.f; }

    bf16x8 BA[4], BB[4];
    float cA, cB;
    LOADB(BA, 0); cA = c2n[col];
#pragma unroll 1
    for (int tp = 0; tp < 32; ++tp) {
        const int t1 = 2 * tp + 1;
        const int t2 = (t1 < 63) ? t1 + 1 : 63;
        // body A: prefetch t1 -> BB, compute t0 from BA
        LOADB(BB, t1); cB = c2n[t1 * 16 + col];
        COMPUTE(BA, cA);
        // body B: prefetch t2 -> BA, compute t1 from BB
        LOADB(BA, t2); cA = c2n[t2 * 16 + col];
        COMPUTE(BB, cB);
    }
#undef COMPUTE
#undef LOADB
#undef UPD

    // reduce (b1, bk, b2) across the 16 lanes holding one row's 16 col-classes (max form)
#pragma unroll
    for (int i = 0; i < 8; ++i) {
        float v1 = b1[i], v2 = b2[i], vk = bk[i];
#pragma unroll
        for (int m = 1; m < 16; m <<= 1) {
            const float o1 = __shfl_xor(v1, m);
            const float o2 = __shfl_xor(v2, m);
            const float ok = __shfl_xor(vk, m);
            v2 = fmaxf(fmaxf(v2, o2), fminf(v1, o1));
            if (o1 > v1) vk = ok;                   // exact tie keeps own; tie flagged anyway
            v1 = fmaxf(v1, o1);
        }
        if (col == 0) {
            const int rt = i >> 2, reg = i & 3;
            const int row = rowbase + rt * 16 + g * 4 + reg;
            out_idx[row] = vk;
            if (v1 - v2 <= MARGIN2) {
                unsigned int p = atomicAdd(qcount, 1u);
                if (p < QCAP) queue[p] = row;
            }
        }
    }
}

// ---- exact fix-up: one block per flagged row, coalesced via transposed codebook ----
__device__ void fix_row(int row, const float* __restrict__ z, const float* __restrict__ cbT,
                        const float* __restrict__ c2, float* __restrict__ out_idx,
                        float* zs, float* rv, int* ri)
{
    const int tid = threadIdx.x;
    __syncthreads();                        // zs safe to overwrite
    if (tid < 16) ((float4*)zs)[tid] = ((const float4*)(z + (size_t)row * DIM))[tid];
    __syncthreads();
    // z2: numpy pairwise, 8 accumulators (verified path), from LDS broadcast
    float ra[8];
#pragma unroll
    for (int j = 0; j < 8; ++j) ra[j] = __fmul_rn(zs[j], zs[j]);
#pragma unroll
    for (int d = 8; d < DIM; d += 8) {
#pragma unroll
        for (int j = 0; j < 8; ++j) ra[j] = __fadd_rn(ra[j], __fmul_rn(zs[d + j], zs[d + j]));
    }
    const float z2 = __fadd_rn(__fadd_rn(__fadd_rn(ra[0], ra[1]), __fadd_rn(ra[2], ra[3])),
                               __fadd_rn(__fadd_rn(ra[4], ra[5]), __fadd_rn(ra[6], ra[7])));
    // 4 contiguous codes per thread: k = 4*tid + j, via cbT (coalesced float4 per d)
    float a[4] = {0.f, 0.f, 0.f, 0.f};
#pragma unroll 8
    for (int d = 0; d < DIM; ++d) {
        const float zd = zs[d];
        const float4 cv = ((const float4*)(cbT + (size_t)d * NCODE))[tid];
        a[0] = __fmaf_rn(zd, cv.x, a[0]);
        a[1] = __fmaf_rn(zd, cv.y, a[1]);
        a[2] = __fmaf_rn(zd, cv.z, a[2]);
        a[3] = __fmaf_rn(zd, cv.w, a[3]);
    }
    const int k0 = tid * 4;
    float best = __builtin_inff();
    int bestk = NCODE;
#pragma unroll
    for (int j = 0; j < 4; ++j) {
        const float dist = __fadd_rn(__fmaf_rn(-2.0f, a[j], z2), c2[k0 + j]);
        if (dist < best) { best = dist; bestk = k0 + j; }   // strict <, ascending k
    }
    rv[tid] = best; ri[tid] = bestk;
    __syncthreads();
#pragma unroll
    for (int s = 128; s > 0; s >>= 1) {
        if (tid < s) {
            const float ov = rv[tid + s]; const int oi = ri[tid + s];
            if (ov < rv[tid] || (ov == rv[tid] && oi < ri[tid])) { rv[tid] = ov; ri[tid] = oi; }
        }
        __syncthreads();
    }
    if (tid == 0) out_idx[row] = (float)ri[0];
}

__global__ __launch_bounds__(256) void fix_kernel(
        const float* __restrict__ z, const float* __restrict__ cbT,
        const float* __restrict__ c2, const int* __restrict__ queue,
        const unsigned int* __restrict__ qcount, float* __restrict__ out_idx)
{
    __shared__ float zs[DIM];
    __shared__ float rv[256];
    __shared__ int   ri[256];
    const unsigned int nq = *qcount;
    if (nq <= QCAP) {
        for (unsigned int qi = blockIdx.x; qi < nq; qi += gridDim.x)
            fix_row(queue[qi], z, cbT, c2, out_idx, zs, rv, ri);
    } else {
        // overflow fallback (never expected): exact-fix every row
        for (int row = blockIdx.x; row < BATCH; row += (int)gridDim.x)
            fix_row(row, z, cbT, c2, out_idx, zs, rv, ri);
    }
}

// ---- epilogue: gather z_q, straight-through out, loss (fused final reduce) ----
__global__ __launch_bounds__(BLOCK) void emit_kernel(
        const float* __restrict__ z, const float* __restrict__ cb,
        const float* __restrict__ out_idx, float* __restrict__ out_zq,
        double* __restrict__ dsum, unsigned int* __restrict__ dcount,
        float* __restrict__ out_loss)
{
    const int b = blockIdx.x * BLOCK + threadIdx.x;
    const int bestk = (int)out_idx[b];
    const float* cq = cb + (size_t)bestk * DIM;
    const float4* zv = (const float4*)(z + (size_t)b * DIM);
    const float4* qv = (const float4*)cq;
    float4* ov = (float4*)(out_zq + (size_t)b * DIM);
    double lsum = 0.0;
#pragma unroll
    for (int i = 0; i < DIM / 4; ++i) {
        float4 qq = qv[i], zl = zv[i];
        float qa[4] = {qq.x, qq.y, qq.z, qq.w};
        float za[4] = {zl.x, zl.y, zl.z, zl.w};
        float o[4];
#pragma unroll
        for (int j = 0; j < 4; ++j) {
            const float t = __fsub_rn(qa[j], za[j]);
            o[j] = __fadd_rn(za[j], t);
            lsum += (double)t * (double)t;
        }
        float4 vv; vv.x = o[0]; vv.y = o[1]; vv.z = o[2]; vv.w = o[3];
        ov[i] = vv;
    }

    __shared__ double sred[BLOCK];
    sred[threadIdx.x] = lsum;
    __syncthreads();
#pragma unroll
    for (int s = BLOCK / 2; s > 0; s >>= 1) {
        if (threadIdx.x < s) sred[threadIdx.x] += sred[threadIdx.x + s];
        __syncthreads();
    }
    if (threadIdx.x == 0) {
        atomicAdd(dsum, sred[0]);               // device-scope f64 atomic (XCD-safe)
        __threadfence();
        const unsigned int p = atomicAdd(dcount, 1u);
        if (p == NBLK - 1) {                    // last block finishes the loss
            __threadfence();
            const double tot = atomicAdd(dsum, 0.0);   // atomic read
            const double mean = tot / (double)((size_t)BATCH * DIM);
            const float L = (float)mean;
            out_loss[0] = __fadd_rn(L, __fmul_rn(0.25f, L));
        }
    }
}

extern "C" void kernel_launch(void* const* d_in, const int* in_sizes, int n_in,
                              void* d_out, int out_size, void* d_ws, size_t ws_size,
                              hipStream_t stream) {
    (void)in_sizes; (void)n_in; (void)out_size; (void)ws_size;
    const float* z  = (const float*)d_in[0];
    const float* cb = (const float*)d_in[1];
    float* out      = (float*)d_out;
    float* out_zq   = out;
    float* out_loss = out + (size_t)BATCH * DIM;
    float* out_idx  = out + (size_t)BATCH * DIM + 1;
    double* dsum    = (double*)d_ws;
    unsigned int* dcount = (unsigned int*)((char*)d_ws + 8);
    unsigned int* qcount = (unsigned int*)((char*)d_ws + 12);
    float* c2       = (float*)((char*)d_ws + 1024);
    float* c2n      = (float*)((char*)d_ws + 5120);
    unsigned short* pack = (unsigned short*)((char*)d_ws + 16384);
    int* queue      = (int*)((char*)d_ws + 278528);
    float* cbT      = (float*)((char*)d_ws + 540672);

    prep_kernel<<<256, 256, 0, stream>>>(cb, c2, c2n, cbT, pack, qcount, dsum, dcount);
    screen_kernel<<<BATCH / 128, 256, 0, stream>>>(z, pack, c2n, out_idx, queue, qcount);
    fix_kernel<<<2048, 256, 0, stream>>>(z, cbT, c2, queue, qcount, out_idx);
    emit_kernel<<<NBLK, BLOCK, 0, stream>>>(z, cb, out_idx, out_zq, dsum, dcount, out_loss);
}

// Round 7
// 363.292 us; speedup vs baseline: 1.0134x; 1.0134x over previous
//
#include <hip/hip_runtime.h>

#define BATCH   262144
#define NCODE   1024
#define DIM     64
#define BLOCK   256
#define NBLK    (BATCH / BLOCK)   // 1024 blocks for emit
#define MARGIN2 2e-5f             // s''-units (= 4e-5 in dist units, validated r2-r6)
#define QCAP    65536

// ws layout (bytes):
// [0, 8)               double dsum            -- fused loss accumulator
// [8, 12)              uint   dcount          -- emit completion counter
// [12, 16)             uint   qcount
// [1024, 5120)         float  c2[1024]
// [5120, 9216)         float  c2n[1024]       -- c2n[k] = -0.5f*c2[k]
// [16384, 278528)      ushort pack[131072]    -- codebook bf16 hi/lo, fragment-major
// [278528, 540672)     int    queue[65536]
// [540672, 802816)     float  cbT[65536]      -- codebook transposed [d][k]

typedef __attribute__((ext_vector_type(8))) short bf16x8;
typedef __attribute__((ext_vector_type(4))) float f32x4;

#define MFMA(a, b, c) __builtin_amdgcn_mfma_f32_16x16x32_bf16(a, b, c, 0, 0, 0)

// fp32 -> bf16 hi (RNE) + bf16 lo (RNE of exact residual)
__device__ __forceinline__ void split1(float f, unsigned short& h, unsigned short& l) {
    unsigned u = __float_as_uint(f);
    unsigned r = (u + 0x7fffu + ((u >> 16) & 1u)) >> 16;
    h = (unsigned short)r;
    float hf = __uint_as_float(r << 16);
    float lo = f - hf;                      // exact (Sterbenz)
    unsigned u2 = __float_as_uint(lo);
    l = (unsigned short)((u2 + 0x7fffu + ((u2 >> 16) & 1u)) >> 16);
}

// ---- fused prep: counters zero, cbT transpose, exact c2 (+ -c2/2), pack ----
__global__ __launch_bounds__(256) void prep_kernel(
        const float* __restrict__ cb, float* __restrict__ c2, float* __restrict__ c2n,
        float* __restrict__ cbT, unsigned short* __restrict__ pack,
        unsigned int* __restrict__ qcount, double* __restrict__ dsum,
        unsigned int* __restrict__ dcount)
{
    const int gid = blockIdx.x * 256 + threadIdx.x;           // 0..65535
    if (gid == 0) { *qcount = 0u; *dsum = 0.0; *dcount = 0u; } // re-zero each replay
    // transpose: cbT[d][k] = cb[k][d]
    cbT[(size_t)(gid & 63) * NCODE + (gid >> 6)] = cb[gid];
    // exact c2 (numpy pairwise order, 8 accumulators) — verified
    if (gid < NCODE) {
        const float* row = cb + (size_t)gid * DIM;
        float r[8];
#pragma unroll
        for (int j = 0; j < 8; ++j) r[j] = __fmul_rn(row[j], row[j]);
#pragma unroll
        for (int i = 8; i < DIM; i += 8) {
#pragma unroll
            for (int j = 0; j < 8; ++j) r[j] = __fadd_rn(r[j], __fmul_rn(row[i + j], row[i + j]));
        }
        const float v = __fadd_rn(__fadd_rn(__fadd_rn(r[0], r[1]), __fadd_rn(r[2], r[3])),
                                  __fadd_rn(__fadd_rn(r[4], r[5]), __fadd_rn(r[6], r[7])));
        c2[gid] = v;
        c2n[gid] = -0.5f * v;                 // exact scaling, screen-side only
    }
    // pack: fragment-major bf16 hi/lo
    if (gid < 4096) {
        const int t = gid >> 6, lane = gid & 63;
        const int c = t * 16 + (lane & 15);
        const int g = lane >> 4;
#pragma unroll
        for (int s = 0; s < 2; ++s) {
            const float* src = cb + (size_t)c * DIM + s * 32 + g * 8;
            bf16x8 hv, lv;
#pragma unroll
            for (int j = 0; j < 8; ++j) {
                unsigned short hh, ll; split1(src[j], hh, ll);
                hv[j] = (short)hh; lv[j] = (short)ll;
            }
            *(bf16x8*)(pack + ((size_t)(t * 4 + 2 * s + 0) * 64 + lane) * 8) = hv;
            *(bf16x8*)(pack + ((size_t)(t * 4 + 2 * s + 1) * 64 + lane) * 8) = lv;
        }
    }
}

// ---- MFMA screening: per-row best/second-best of s''(k) = cross(k) - c2[k]/2 ----
// argmax(s'') == argmin(dist). wave = 64 rows (rt=4); block = 4 waves; grid = 1024.
// Wave-private double-buffered 4 KB LDS tiles via global_load_lds; self-sync by
// s_waitcnt vmcnt(0) at loop top (prefetch had a full compute phase to land).
// NO __syncthreads in the K-loop -> no convoys, no drain of other waves' work.
__global__ __launch_bounds__(256, 3) void screen_kernel(
        const float* __restrict__ z, const unsigned short* __restrict__ pack,
        const float* __restrict__ c2n, float* __restrict__ out_idx,
        int* __restrict__ queue, unsigned int* __restrict__ qcount)
{
    __shared__ __align__(16) unsigned short ldsb[4][2][2048];  // 4 waves x 2 x 4 KB
    __shared__ float c2s[NCODE];                               // 4 KB
    const int tid  = threadIdx.x;
    const int lane = tid & 63, wid = tid >> 6;
    const int col  = lane & 15, g = lane >> 4;
    const int rowbase = blockIdx.x * 256 + wid * 64;

    // stage c2n to LDS (one block barrier, outside the K-loop)
    ((float4*)c2s)[tid] = ((const float4*)c2n)[tid];

    // A-frags: A[row = lane&15][k = 32*s + 8*g + j], in VGPRs for whole kernel
    bf16x8 Ah[4][2], Al[4][2];
#pragma unroll
    for (int rt = 0; rt < 4; ++rt)
#pragma unroll
        for (int s = 0; s < 2; ++s) {
            const float* zp = z + (size_t)(rowbase + rt * 16 + col) * DIM + s * 32 + g * 8;
            float tmp[8];
            *(float4*)(tmp)     = ((const float4*)zp)[0];
            *(float4*)(tmp + 4) = ((const float4*)zp)[1];
            bf16x8 hv, lv;
#pragma unroll
            for (int j = 0; j < 8; ++j) {
                unsigned short hh, ll; split1(tmp[j], hh, ll);
                hv[j] = (short)hh; lv[j] = (short)ll;
            }
            Ah[rt][s] = hv; Al[rt][s] = lv;
        }

    float b1[16], b2[16], bk[16];
#pragma unroll
    for (int i = 0; i < 16; ++i) {
        b1[i] = -__builtin_inff(); b2[i] = -__builtin_inff(); bk[i] = 0.f;
    }
    float codef = (float)col;

    // max-tracking; b2 = med3(s, b1_old, b2) is exact 2nd-max update given b2 <= b1
#define UPD(i, sv) { const float s_ = (sv); \
                     bk[i] = (s_ > b1[i]) ? codef : bk[i]; \
                     b2[i] = __builtin_amdgcn_fmed3f(s_, b1[i], b2[i]); \
                     b1[i] = fmaxf(b1[i], s_); }

    // stage one 4 KB tile into this wave's LDS buffer (4 x global_load_lds width-16)
#define STAGE(t, buf) { \
_Pragma("unroll") \
        for (int i_ = 0; i_ < 4; ++i_) { \
            const unsigned short* g_ = pack + (size_t)(t) * 2048 + i_ * 512 + lane * 8; \
            unsigned short* l_ = &ldsb[wid][buf][i_ * 512]; \
            __builtin_amdgcn_global_load_lds( \
                (const __attribute__((address_space(1))) unsigned int*)g_, \
                (__attribute__((address_space(3))) unsigned int*)l_, 16, 0, 0); \
        } }

    STAGE(0, 0);
    __syncthreads();                        // c2s ready (also drains stage 0: harmless)
#pragma unroll 1
    for (int t = 0; t < 64; ++t) {
        const int cur = t & 1;
        asm volatile("s_waitcnt vmcnt(0)" ::: "memory");   // this wave's tile t is in LDS
        const unsigned short* lb = &ldsb[wid][cur][0];
        bf16x8 B0 = *(const bf16x8*)(lb +    0 + lane * 8);   // Bh0
        bf16x8 B1 = *(const bf16x8*)(lb +  512 + lane * 8);   // Bl0
        bf16x8 B2 = *(const bf16x8*)(lb + 1024 + lane * 8);   // Bh1
        bf16x8 B3 = *(const bf16x8*)(lb + 1536 + lane * 8);   // Bl1
        if (t < 63) STAGE(t + 1, cur ^ 1);                    // prefetch under compute
        const float cv = c2s[t * 16 + col];
#pragma unroll
        for (int rt = 0; rt < 4; ++rt) {
            f32x4 acc = {cv, cv, cv, cv};   // C-in = -c2/2 folds the distance fma away
            // cross = zhi*chi + zhi*clo + zlo*chi (lo*lo dropped, ~2^-18 rel)
            acc = MFMA(Ah[rt][0], B0, acc); acc = MFMA(Ah[rt][1], B2, acc);
            acc = MFMA(Ah[rt][0], B1, acc); acc = MFMA(Al[rt][0], B0, acc);
            acc = MFMA(Ah[rt][1], B3, acc); acc = MFMA(Al[rt][1], B2, acc);
#pragma unroll
            for (int reg = 0; reg < 4; ++reg) UPD(rt * 4 + reg, acc[reg]);
        }
        codef += 16.f;
    }
#undef UPD
#undef STAGE

    // reduce (b1, bk, b2) across the 16 lanes holding one row's 16 col-classes (max form)
#pragma unroll
    for (int i = 0; i < 16; ++i) {
        float v1 = b1[i], v2 = b2[i], vk = bk[i];
#pragma unroll
        for (int m = 1; m < 16; m <<= 1) {
            const float o1 = __shfl_xor(v1, m);
            const float o2 = __shfl_xor(v2, m);
            const float ok = __shfl_xor(vk, m);
            v2 = fmaxf(fmaxf(v2, o2), fminf(v1, o1));
            if (o1 > v1) vk = ok;                   // exact tie keeps own; tie flagged anyway
            v1 = fmaxf(v1, o1);
        }
        if (col == 0) {
            const int rt = i >> 2, reg = i & 3;
            const int row = rowbase + rt * 16 + g * 4 + reg;
            out_idx[row] = vk;
            if (v1 - v2 <= MARGIN2) {
                unsigned int p = atomicAdd(qcount, 1u);
                if (p < QCAP) queue[p] = row;
            }
        }
    }
}

// ---- exact fix-up: one block per flagged row, coalesced via transposed codebook ----
__device__ void fix_row(int row, const float* __restrict__ z, const float* __restrict__ cbT,
                        const float* __restrict__ c2, float* __restrict__ out_idx,
                        float* zs, float* rv, int* ri)
{
    const int tid = threadIdx.x;
    __syncthreads();                        // zs safe to overwrite
    if (tid < 16) ((float4*)zs)[tid] = ((const float4*)(z + (size_t)row * DIM))[tid];
    __syncthreads();
    // z2: numpy pairwise, 8 accumulators (verified path), from LDS broadcast
    float ra[8];
#pragma unroll
    for (int j = 0; j < 8; ++j) ra[j] = __fmul_rn(zs[j], zs[j]);
#pragma unroll
    for (int d = 8; d < DIM; d += 8) {
#pragma unroll
        for (int j = 0; j < 8; ++j) ra[j] = __fadd_rn(ra[j], __fmul_rn(zs[d + j], zs[d + j]));
    }
    const float z2 = __fadd_rn(__fadd_rn(__fadd_rn(ra[0], ra[1]), __fadd_rn(ra[2], ra[3])),
                               __fadd_rn(__fadd_rn(ra[4], ra[5]), __fadd_rn(ra[6], ra[7])));
    // 4 contiguous codes per thread: k = 4*tid + j, via cbT (coalesced float4 per d)
    float a[4] = {0.f, 0.f, 0.f, 0.f};
#pragma unroll 8
    for (int d = 0; d < DIM; ++d) {
        const float zd = zs[d];
        const float4 cv = ((const float4*)(cbT + (size_t)d * NCODE))[tid];
        a[0] = __fmaf_rn(zd, cv.x, a[0]);
        a[1] = __fmaf_rn(zd, cv.y, a[1]);
        a[2] = __fmaf_rn(zd, cv.z, a[2]);
        a[3] = __fmaf_rn(zd, cv.w, a[3]);
    }
    const int k0 = tid * 4;
    float best = __builtin_inff();
    int bestk = NCODE;
#pragma unroll
    for (int j = 0; j < 4; ++j) {
        const float dist = __fadd_rn(__fmaf_rn(-2.0f, a[j], z2), c2[k0 + j]);
        if (dist < best) { best = dist; bestk = k0 + j; }   // strict <, ascending k
    }
    rv[tid] = best; ri[tid] = bestk;
    __syncthreads();
#pragma unroll
    for (int s = 128; s > 0; s >>= 1) {
        if (tid < s) {
            const float ov = rv[tid + s]; const int oi = ri[tid + s];
            if (ov < rv[tid] || (ov == rv[tid] && oi < ri[tid])) { rv[tid] = ov; ri[tid] = oi; }
        }
        __syncthreads();
    }
    if (tid == 0) out_idx[row] = (float)ri[0];
}

__global__ __launch_bounds__(256) void fix_kernel(
        const float* __restrict__ z, const float* __restrict__ cbT,
        const float* __restrict__ c2, const int* __restrict__ queue,
        const unsigned int* __restrict__ qcount, float* __restrict__ out_idx)
{
    __shared__ float zs[DIM];
    __shared__ float rv[256];
    __shared__ int   ri[256];
    const unsigned int nq = *qcount;
    if (nq <= QCAP) {
        for (unsigned int qi = blockIdx.x; qi < nq; qi += gridDim.x)
            fix_row(queue[qi], z, cbT, c2, out_idx, zs, rv, ri);
    } else {
        // overflow fallback (never expected): exact-fix every row
        for (int row = blockIdx.x; row < BATCH; row += (int)gridDim.x)
            fix_row(row, z, cbT, c2, out_idx, zs, rv, ri);
    }
}

// ---- epilogue: gather z_q, straight-through out, loss (fused final reduce) ----
__global__ __launch_bounds__(BLOCK) void emit_kernel(
        const float* __restrict__ z, const float* __restrict__ cb,
        const float* __restrict__ out_idx, float* __restrict__ out_zq,
        double* __restrict__ dsum, unsigned int* __restrict__ dcount,
        float* __restrict__ out_loss)
{
    const int b = blockIdx.x * BLOCK + threadIdx.x;
    const int bestk = (int)out_idx[b];
    const float* cq = cb + (size_t)bestk * DIM;
    const float4* zv = (const float4*)(z + (size_t)b * DIM);
    const float4* qv = (const float4*)cq;
    float4* ov = (float4*)(out_zq + (size_t)b * DIM);
    double lsum = 0.0;
#pragma unroll
    for (int i = 0; i < DIM / 4; ++i) {
        float4 qq = qv[i], zl = zv[i];
        float qa[4] = {qq.x, qq.y, qq.z, qq.w};
        float za[4] = {zl.x, zl.y, zl.z, zl.w};
        float o[4];
#pragma unroll
        for (int j = 0; j < 4; ++j) {
            const float t = __fsub_rn(qa[j], za[j]);
            o[j] = __fadd_rn(za[j], t);
            lsum += (double)t * (double)t;
        }
        float4 vv; vv.x = o[0]; vv.y = o[1]; vv.z = o[2]; vv.w = o[3];
        ov[i] = vv;
    }

    __shared__ double sred[BLOCK];
    sred[threadIdx.x] = lsum;
    __syncthreads();
#pragma unroll
    for (int s = BLOCK / 2; s > 0; s >>= 1) {
        if (threadIdx.x < s) sred[threadIdx.x] += sred[threadIdx.x + s];
        __syncthreads();
    }
    if (threadIdx.x == 0) {
        atomicAdd(dsum, sred[0]);               // device-scope f64 atomic (XCD-safe)
        __threadfence();
        const unsigned int p = atomicAdd(dcount, 1u);
        if (p == NBLK - 1) {                    // last block finishes the loss
            __threadfence();
            const double tot = atomicAdd(dsum, 0.0);   // atomic read
            const double mean = tot / (double)((size_t)BATCH * DIM);
            const float L = (float)mean;
            out_loss[0] = __fadd_rn(L, __fmul_rn(0.25f, L));
        }
    }
}

extern "C" void kernel_launch(void* const* d_in, const int* in_sizes, int n_in,
                              void* d_out, int out_size, void* d_ws, size_t ws_size,
                              hipStream_t stream) {
    (void)in_sizes; (void)n_in; (void)out_size; (void)ws_size;
    const float* z  = (const float*)d_in[0];
    const float* cb = (const float*)d_in[1];
    float* out      = (float*)d_out;
    float* out_zq   = out;
    float* out_loss = out + (size_t)BATCH * DIM;
    float* out_idx  = out + (size_t)BATCH * DIM + 1;
    double* dsum    = (double*)d_ws;
    unsigned int* dcount = (unsigned int*)((char*)d_ws + 8);
    unsigned int* qcount = (unsigned int*)((char*)d_ws + 12);
    float* c2       = (float*)((char*)d_ws + 1024);
    float* c2n      = (float*)((char*)d_ws + 5120);
    unsigned short* pack = (unsigned short*)((char*)d_ws + 16384);
    int* queue      = (int*)((char*)d_ws + 278528);
    float* cbT      = (float*)((char*)d_ws + 540672);

    prep_kernel<<<256, 256, 0, stream>>>(cb, c2, c2n, cbT, pack, qcount, dsum, dcount);
    screen_kernel<<<BATCH / 256, 256, 0, stream>>>(z, pack, c2n, out_idx, queue, qcount);
    fix_kernel<<<2048, 256, 0, stream>>>(z, cbT, c2, queue, qcount, out_idx);
    emit_kernel<<<NBLK, BLOCK, 0, stream>>>(z, cb, out_idx, out_zq, dsum, dcount, out_loss);
}